// Round 1
// baseline (370.582 us; speedup 1.0000x reference)
//
#include <hip/hip_runtime.h>

// Mamba block forward, f32 correctness-first baseline.
// Sizes fixed by the reference.
constexpr int B  = 2, L = 1024, DM = 512, DI = 1024, NST = 16, PW = 97;
constexpr int ML = B * L;               // 2048 rows
constexpr int NCHUNK = 8, CL = L / NCHUNK; // 8 chunks x 128 steps

#define DEV_INLINE __device__ __forceinline__

DEV_INLINE float sigmoidf_(float x) { return 1.f / (1.f + __expf(-x)); }

// ---------------------------------------------------------------------------
// C(M,N) = A(M,K) @ W(N,K)^T   (both row-major; M,N multiples of 64, K of 16)
// 64x64 tile, 256 threads, 4x4 micro-tile per thread.
// ---------------------------------------------------------------------------
__global__ __launch_bounds__(256) void gemm_bt_f32(
    const float* __restrict__ A, const float* __restrict__ W,
    float* __restrict__ C, int M, int N, int K) {
  __shared__ float As[16][68];   // [k][m], padded to keep 16B alignment
  __shared__ float Ws[16][68];   // [k][n]
  const int tid = threadIdx.x;
  const int tx = tid & 15, ty = tid >> 4;
  const int bm = blockIdx.y * 64, bn = blockIdx.x * 64;
  float acc[4][4] = {};
  for (int k0 = 0; k0 < K; k0 += 16) {
    const int r = tid >> 2, c4 = (tid & 3) * 4;
    float4 av = *(const float4*)(A + (size_t)(bm + r) * K + k0 + c4);
    float4 wv = *(const float4*)(W + (size_t)(bn + r) * K + k0 + c4);
    As[c4 + 0][r] = av.x; As[c4 + 1][r] = av.y; As[c4 + 2][r] = av.z; As[c4 + 3][r] = av.w;
    Ws[c4 + 0][r] = wv.x; Ws[c4 + 1][r] = wv.y; Ws[c4 + 2][r] = wv.z; Ws[c4 + 3][r] = wv.w;
    __syncthreads();
#pragma unroll
    for (int kk = 0; kk < 16; ++kk) {
      float a[4], b[4];
#pragma unroll
      for (int i = 0; i < 4; ++i) a[i] = As[kk][ty * 4 + i];
#pragma unroll
      for (int j = 0; j < 4; ++j) b[j] = Ws[kk][tx * 4 + j];
#pragma unroll
      for (int i = 0; i < 4; ++i)
#pragma unroll
        for (int j = 0; j < 4; ++j) acc[i][j] = fmaf(a[i], b[j], acc[i][j]);
    }
    __syncthreads();
  }
#pragma unroll
  for (int i = 0; i < 4; ++i) {
    float4 v = make_float4(acc[i][0], acc[i][1], acc[i][2], acc[i][3]);
    *(float4*)(C + (size_t)(bm + ty * 4 + i) * N + bn + tx * 4) = v;
  }
}

// ---------------------------------------------------------------------------
// causal depthwise conv (K=3, left pad 2) + bias + SiLU.  xi = xz[:, :DI]
// ---------------------------------------------------------------------------
__global__ __launch_bounds__(256) void conv_silu_k(
    const float* __restrict__ xz, const float* __restrict__ cw,
    const float* __restrict__ cb, float* __restrict__ xc) {
  int idx = blockIdx.x * 256 + threadIdx.x;   // (m,d)
  int m = idx >> 10, d = idx & 1023;
  int t = m & (L - 1);
  float w0 = cw[d * 3 + 0], w1 = cw[d * 3 + 1], w2 = cw[d * 3 + 2];
  float v = cb[d];
  v = fmaf(xz[(size_t)m * (2 * DI) + d], w2, v);
  if (t >= 1) v = fmaf(xz[(size_t)(m - 1) * (2 * DI) + d], w1, v);
  if (t >= 2) v = fmaf(xz[(size_t)(m - 2) * (2 * DI) + d], w0, v);
  xc[idx] = v * sigmoidf_(v);
}

// ---------------------------------------------------------------------------
// proj = xc @ x_proj_w^T : (ML,1024) x (97,1024)^T -> (ML,97)
// one block = 4 rows staged in LDS; 97 active lanes each do 4 dots.
// ---------------------------------------------------------------------------
__global__ __launch_bounds__(128) void proj_k(
    const float* __restrict__ xc, const float* __restrict__ xw,
    float* __restrict__ proj) {
  __shared__ float xs[4][DI];
  int m0 = blockIdx.x * 4;
  for (int i = threadIdx.x; i < 4 * DI; i += 128)
    xs[i >> 10][i & 1023] = xc[(size_t)m0 * DI + i];
  __syncthreads();
  int n = threadIdx.x;
  if (n >= PW) return;
  const float* wr = xw + (size_t)n * DI;
  float s0 = 0.f, s1 = 0.f, s2 = 0.f, s3 = 0.f;
#pragma unroll 4
  for (int k = 0; k < DI; k += 4) {
    float4 w4 = *(const float4*)(wr + k);
    s0 = fmaf(xs[0][k], w4.x, s0); s0 = fmaf(xs[0][k + 1], w4.y, s0);
    s0 = fmaf(xs[0][k + 2], w4.z, s0); s0 = fmaf(xs[0][k + 3], w4.w, s0);
    s1 = fmaf(xs[1][k], w4.x, s1); s1 = fmaf(xs[1][k + 1], w4.y, s1);
    s1 = fmaf(xs[1][k + 2], w4.z, s1); s1 = fmaf(xs[1][k + 3], w4.w, s1);
    s2 = fmaf(xs[2][k], w4.x, s2); s2 = fmaf(xs[2][k + 1], w4.y, s2);
    s2 = fmaf(xs[2][k + 2], w4.z, s2); s2 = fmaf(xs[2][k + 3], w4.w, s2);
    s3 = fmaf(xs[3][k], w4.x, s3); s3 = fmaf(xs[3][k + 1], w4.y, s3);
    s3 = fmaf(xs[3][k + 2], w4.z, s3); s3 = fmaf(xs[3][k + 3], w4.w, s3);
  }
  proj[(size_t)(m0 + 0) * PW + n] = s0;
  proj[(size_t)(m0 + 1) * PW + n] = s1;
  proj[(size_t)(m0 + 2) * PW + n] = s2;
  proj[(size_t)(m0 + 3) * PW + n] = s3;
}

// ---------------------------------------------------------------------------
// delta = softplus(proj[:, :32] @ dt_w^T + dt_b) : (ML,1024)
// block: 256 d-channels x 8 m-rows. dt_w tile staged in LDS (padded).
// ---------------------------------------------------------------------------
__global__ __launch_bounds__(256) void delta_k(
    const float* __restrict__ proj, const float* __restrict__ dtw,
    const float* __restrict__ dtb, float* __restrict__ delta) {
  __shared__ float ws[256][33];
  __shared__ float ps[8][32];
  const int tid = threadIdx.x;
  const int d0 = blockIdx.x * 256;
  const int m0 = blockIdx.y * 8;
#pragma unroll
  for (int j = 0; j < 8; ++j) {
    int flat = tid * 4 + j * 1024;
    int r = flat >> 5, c = flat & 31;
    float4 v = *(const float4*)(dtw + (size_t)d0 * 32 + flat);
    ws[r][c] = v.x; ws[r][c + 1] = v.y; ws[r][c + 2] = v.z; ws[r][c + 3] = v.w;
  }
  { int i = tid >> 5, r = tid & 31;
    ps[i][r] = proj[(size_t)(m0 + i) * PW + r]; }
  __syncthreads();
  float s[8];
  float bias = dtb[d0 + tid];
#pragma unroll
  for (int i = 0; i < 8; ++i) s[i] = bias;
#pragma unroll
  for (int r = 0; r < 32; ++r) {
    float wv = ws[tid][r];
#pragma unroll
    for (int i = 0; i < 8; ++i) s[i] = fmaf(ps[i][r], wv, s[i]);
  }
#pragma unroll
  for (int i = 0; i < 8; ++i) {
    float x = s[i];
    float sp = (x > 20.f) ? x : log1pf(__expf(x));
    delta[(size_t)(m0 + i) * DI + d0 + tid] = sp;
  }
}

// ---------------------------------------------------------------------------
// Chunked selective scan (complex, trapezoidal).
// lane = n (0..15) within 16-lane group; 16 (b,d) channels per block.
// PASS_B=false: compute per-chunk aggregates (prod alpha, U).
// PASS_B=true : rescan from hprev, emit ybuf = (y + D*xc) * silu(z).
// ---------------------------------------------------------------------------
template <bool PASS_B>
__global__ __launch_bounds__(256) void scan_pass(
    const float* __restrict__ proj, const float* __restrict__ delta,
    const float* __restrict__ xc, const float* __restrict__ xz,
    const float* __restrict__ A_log, const float* __restrict__ A_imag,
    const float* __restrict__ D_skip,
    float* __restrict__ aggAr, float* __restrict__ aggAi,
    float* __restrict__ aggUr, float* __restrict__ aggUi,
    const float* __restrict__ hpR, const float* __restrict__ hpI,
    float* __restrict__ ybuf) {
  const int tid = threadIdx.x;
  const int n = tid & 15;
  const int gch = blockIdx.x * 16 + (tid >> 4);  // (b,d) channel, 0..2047
  const int c = blockIdx.y;                      // chunk
  const int b = gch >> 10, d = gch & 1023;
  const float Ar = -__expf(A_log[d * 16 + n]);
  const float Ai = A_imag[d * 16 + n];
  const int t0 = c * CL;
  const int mb = b * L;

  float Bxpr = 0.f, Bxpi = 0.f;
  if (t0 > 0) {  // Bx_prev for the first step of this chunk
    int mp = mb + t0 - 1;
    float xp = xc[(size_t)mp * DI + d];
    Bxpr = proj[(size_t)mp * PW + 32 + n] * xp;
    Bxpi = proj[(size_t)mp * PW + 48 + n] * xp;
  }
  float hr, hi, Aar = 1.f, Aai = 0.f, Dsk = 0.f;
  if (PASS_B) {
    int idx = c * 32768 + blockIdx.x * 256 + tid;
    hr = hpR[idx]; hi = hpI[idx];
    Dsk = D_skip[d];
  } else {
    hr = 0.f; hi = 0.f;
  }

#pragma unroll 2
  for (int t = t0; t < t0 + CL; ++t) {
    const int m = mb + t;
    const float* row = proj + (size_t)m * PW;
    float Br = row[32 + n], Bi = row[48 + n];
    float dlt = delta[(size_t)m * DI + d];
    float xt = xc[(size_t)m * DI + d];
    float lam = sigmoidf_(row[96]);
    float ear = __expf(dlt * Ar);
    float sn, cs; __sincosf(dlt * Ai, &sn, &cs);
    float ar = ear * cs, ai = ear * sn;
    float Bxr = Br * xt, Bxi = Bi * xt;
    float bsc = (1.f - lam) * dlt, g = lam * dlt;
    float ur = bsc * (ar * Bxpr - ai * Bxpi) + g * Bxr;
    float ui = bsc * (ar * Bxpi + ai * Bxpr) + g * Bxi;
    float nhr = ar * hr - ai * hi + ur;
    float nhi = ar * hi + ai * hr + ui;
    hr = nhr; hi = nhi;
    if (!PASS_B) {
      float nAr = Aar * ar - Aai * ai, nAi = Aar * ai + Aai * ar;
      Aar = nAr; Aai = nAi;
    }
    Bxpr = Bxr; Bxpi = Bxi;
    if (PASS_B) {
      float Cr = row[64 + n], Ci = row[80 + n];
      float yc = hr * Cr + hi * Ci;           // Re(h * conj(C))
      yc += __shfl_xor(yc, 1);
      yc += __shfl_xor(yc, 2);
      yc += __shfl_xor(yc, 4);
      yc += __shfl_xor(yc, 8);
      if (n == 0) {
        float y = yc + Dsk * xt;
        float zt = xz[(size_t)m * (2 * DI) + DI + d];
        ybuf[(size_t)m * DI + d] = y * (zt * sigmoidf_(zt));
      }
    }
  }
  if (!PASS_B) {
    int idx = c * 32768 + blockIdx.x * 256 + tid;
    aggAr[idx] = Aar; aggAi[idx] = Aai; aggUr[idx] = hr; aggUi[idx] = hi;
  }
}

// sequential combine of the 8 chunk aggregates -> chunk-entry states
__global__ __launch_bounds__(256) void scan_combine_k(
    const float* __restrict__ aggAr, const float* __restrict__ aggAi,
    const float* __restrict__ aggUr, const float* __restrict__ aggUi,
    float* __restrict__ hpR, float* __restrict__ hpI) {
  int gid = blockIdx.x * 256 + threadIdx.x;   // (b,d,n) lane
  float hr = 0.f, hi = 0.f;
#pragma unroll
  for (int c = 0; c < NCHUNK; ++c) {
    int idx = c * 32768 + gid;
    hpR[idx] = hr; hpI[idx] = hi;
    float ar = aggAr[idx], ai = aggAi[idx];
    float nr = ar * hr - ai * hi + aggUr[idx];
    float ni = ar * hi + ai * hr + aggUi[idx];
    hr = nr; hi = ni;
  }
}

extern "C" void kernel_launch(void* const* d_in, const int* in_sizes, int n_in,
                              void* d_out, int out_size, void* d_ws, size_t ws_size,
                              hipStream_t stream) {
  const float* x        = (const float*)d_in[0];
  const float* in_proj  = (const float*)d_in[1];
  const float* conv_w   = (const float*)d_in[2];
  const float* conv_b   = (const float*)d_in[3];
  const float* x_proj_w = (const float*)d_in[4];
  const float* dt_w     = (const float*)d_in[5];
  const float* dt_b     = (const float*)d_in[6];
  const float* A_log    = (const float*)d_in[7];
  const float* A_imag   = (const float*)d_in[8];
  const float* D_skip   = (const float*)d_in[9];
  const float* out_proj = (const float*)d_in[10];
  float* out = (float*)d_out;

  float* ws = (float*)d_ws;
  float* xz    = ws; ws += (size_t)ML * 2 * DI;   // 4,194,304
  float* xc    = ws; ws += (size_t)ML * DI;       // 2,097,152
  float* proj  = ws; ws += (size_t)ML * PW;       //   198,656
  float* delta = ws; ws += (size_t)ML * DI;       // 2,097,152
  float* ybuf  = ws; ws += (size_t)ML * DI;       // 2,097,152
  float* aggAr = ws; ws += 262144;
  float* aggAi = ws; ws += 262144;
  float* aggUr = ws; ws += 262144;
  float* aggUi = ws; ws += 262144;
  float* hpR   = ws; ws += 262144;
  float* hpI   = ws; ws += 262144;                // total ~49 MB

  gemm_bt_f32<<<dim3(2 * DI / 64, ML / 64), 256, 0, stream>>>(x, in_proj, xz, ML, 2 * DI, DM);
  conv_silu_k<<<ML * DI / 256, 256, 0, stream>>>(xz, conv_w, conv_b, xc);
  proj_k<<<ML / 4, 128, 0, stream>>>(xc, x_proj_w, proj);
  delta_k<<<dim3(DI / 256, ML / 8), 256, 0, stream>>>(proj, dt_w, dt_b, delta);
  scan_pass<false><<<dim3(128, NCHUNK), 256, 0, stream>>>(
      proj, delta, xc, xz, A_log, A_imag, D_skip,
      aggAr, aggAi, aggUr, aggUi, nullptr, nullptr, nullptr);
  scan_combine_k<<<128, 256, 0, stream>>>(aggAr, aggAi, aggUr, aggUi, hpR, hpI);
  scan_pass<true><<<dim3(128, NCHUNK), 256, 0, stream>>>(
      proj, delta, xc, xz, A_log, A_imag, D_skip,
      nullptr, nullptr, nullptr, nullptr, hpR, hpI, ybuf);
  gemm_bt_f32<<<dim3(DM / 64, ML / 64), 256, 0, stream>>>(ybuf, out_proj, out, ML, DM, DI);
}

// Round 2
// 306.619 us; speedup vs baseline: 1.2086x; 1.2086x over previous
//
#include <hip/hip_runtime.h>

// Mamba block forward, f32. Round 2: scan parallelism (NCHUNK=16),
// sigmoid(lam) folded into proj_k, combine fused into pass B.
constexpr int B  = 2, L = 1024, DM = 512, DI = 1024, NST = 16, PW = 97;
constexpr int ML = B * L;                   // 2048 rows
constexpr int NCHUNK = 16, CL = L / NCHUNK; // 16 chunks x 64 steps
constexpr int NLANES = B * DI * NST;        // 32768 scan lanes

#define DEV_INLINE __device__ __forceinline__

DEV_INLINE float sigmoidf_(float x) { return 1.f / (1.f + __expf(-x)); }

// ---------------------------------------------------------------------------
// C(M,N) = A(M,K) @ W(N,K)^T   (both row-major; M,N multiples of 64, K of 16)
// 64x64 tile, 256 threads, 4x4 micro-tile per thread.
// ---------------------------------------------------------------------------
__global__ __launch_bounds__(256) void gemm_bt_f32(
    const float* __restrict__ A, const float* __restrict__ W,
    float* __restrict__ C, int M, int N, int K) {
  __shared__ float As[16][68];   // [k][m], padded to keep 16B alignment
  __shared__ float Ws[16][68];   // [k][n]
  const int tid = threadIdx.x;
  const int tx = tid & 15, ty = tid >> 4;
  const int bm = blockIdx.y * 64, bn = blockIdx.x * 64;
  float acc[4][4] = {};
  for (int k0 = 0; k0 < K; k0 += 16) {
    const int r = tid >> 2, c4 = (tid & 3) * 4;
    float4 av = *(const float4*)(A + (size_t)(bm + r) * K + k0 + c4);
    float4 wv = *(const float4*)(W + (size_t)(bn + r) * K + k0 + c4);
    As[c4 + 0][r] = av.x; As[c4 + 1][r] = av.y; As[c4 + 2][r] = av.z; As[c4 + 3][r] = av.w;
    Ws[c4 + 0][r] = wv.x; Ws[c4 + 1][r] = wv.y; Ws[c4 + 2][r] = wv.z; Ws[c4 + 3][r] = wv.w;
    __syncthreads();
#pragma unroll
    for (int kk = 0; kk < 16; ++kk) {
      float a[4], b[4];
#pragma unroll
      for (int i = 0; i < 4; ++i) a[i] = As[kk][ty * 4 + i];
#pragma unroll
      for (int j = 0; j < 4; ++j) b[j] = Ws[kk][tx * 4 + j];
#pragma unroll
      for (int i = 0; i < 4; ++i)
#pragma unroll
        for (int j = 0; j < 4; ++j) acc[i][j] = fmaf(a[i], b[j], acc[i][j]);
    }
    __syncthreads();
  }
#pragma unroll
  for (int i = 0; i < 4; ++i) {
    float4 v = make_float4(acc[i][0], acc[i][1], acc[i][2], acc[i][3]);
    *(float4*)(C + (size_t)(bm + ty * 4 + i) * N + bn + tx * 4) = v;
  }
}

// ---------------------------------------------------------------------------
// causal depthwise conv (K=3, left pad 2) + bias + SiLU.  xi = xz[:, :DI]
// ---------------------------------------------------------------------------
__global__ __launch_bounds__(256) void conv_silu_k(
    const float* __restrict__ xz, const float* __restrict__ cw,
    const float* __restrict__ cb, float* __restrict__ xc) {
  int idx = blockIdx.x * 256 + threadIdx.x;   // (m,d)
  int m = idx >> 10, d = idx & 1023;
  int t = m & (L - 1);
  float w0 = cw[d * 3 + 0], w1 = cw[d * 3 + 1], w2 = cw[d * 3 + 2];
  float v = cb[d];
  v = fmaf(xz[(size_t)m * (2 * DI) + d], w2, v);
  if (t >= 1) v = fmaf(xz[(size_t)(m - 1) * (2 * DI) + d], w1, v);
  if (t >= 2) v = fmaf(xz[(size_t)(m - 2) * (2 * DI) + d], w0, v);
  xc[idx] = v * sigmoidf_(v);
}

// ---------------------------------------------------------------------------
// proj = xc @ x_proj_w^T : (ML,1024) x (97,1024)^T -> (ML,97)
// Column 96 (lambda) is stored PRE-SIGMOIDED (only the scan reads it).
// ---------------------------------------------------------------------------
__global__ __launch_bounds__(128) void proj_k(
    const float* __restrict__ xc, const float* __restrict__ xw,
    float* __restrict__ proj) {
  __shared__ float xs[4][DI];
  int m0 = blockIdx.x * 4;
  for (int i = threadIdx.x; i < 4 * DI; i += 128)
    xs[i >> 10][i & 1023] = xc[(size_t)m0 * DI + i];
  __syncthreads();
  int n = threadIdx.x;
  if (n >= PW) return;
  const float* wr = xw + (size_t)n * DI;
  float s0 = 0.f, s1 = 0.f, s2 = 0.f, s3 = 0.f;
#pragma unroll 4
  for (int k = 0; k < DI; k += 4) {
    float4 w4 = *(const float4*)(wr + k);
    s0 = fmaf(xs[0][k], w4.x, s0); s0 = fmaf(xs[0][k + 1], w4.y, s0);
    s0 = fmaf(xs[0][k + 2], w4.z, s0); s0 = fmaf(xs[0][k + 3], w4.w, s0);
    s1 = fmaf(xs[1][k], w4.x, s1); s1 = fmaf(xs[1][k + 1], w4.y, s1);
    s1 = fmaf(xs[1][k + 2], w4.z, s1); s1 = fmaf(xs[1][k + 3], w4.w, s1);
    s2 = fmaf(xs[2][k], w4.x, s2); s2 = fmaf(xs[2][k + 1], w4.y, s2);
    s2 = fmaf(xs[2][k + 2], w4.z, s2); s2 = fmaf(xs[2][k + 3], w4.w, s2);
    s3 = fmaf(xs[3][k], w4.x, s3); s3 = fmaf(xs[3][k + 1], w4.y, s3);
    s3 = fmaf(xs[3][k + 2], w4.z, s3); s3 = fmaf(xs[3][k + 3], w4.w, s3);
  }
  if (n == PW - 1) {      // lambda column: store sigmoid(lam) directly
    s0 = sigmoidf_(s0); s1 = sigmoidf_(s1); s2 = sigmoidf_(s2); s3 = sigmoidf_(s3);
  }
  proj[(size_t)(m0 + 0) * PW + n] = s0;
  proj[(size_t)(m0 + 1) * PW + n] = s1;
  proj[(size_t)(m0 + 2) * PW + n] = s2;
  proj[(size_t)(m0 + 3) * PW + n] = s3;
}

// ---------------------------------------------------------------------------
// delta = softplus(proj[:, :32] @ dt_w^T + dt_b) : (ML,1024)
// ---------------------------------------------------------------------------
__global__ __launch_bounds__(256) void delta_k(
    const float* __restrict__ proj, const float* __restrict__ dtw,
    const float* __restrict__ dtb, float* __restrict__ delta) {
  __shared__ float ws[256][33];
  __shared__ float ps[8][32];
  const int tid = threadIdx.x;
  const int d0 = blockIdx.x * 256;
  const int m0 = blockIdx.y * 8;
#pragma unroll
  for (int j = 0; j < 8; ++j) {
    int flat = tid * 4 + j * 1024;
    int r = flat >> 5, c = flat & 31;
    float4 v = *(const float4*)(dtw + (size_t)d0 * 32 + flat);
    ws[r][c] = v.x; ws[r][c + 1] = v.y; ws[r][c + 2] = v.z; ws[r][c + 3] = v.w;
  }
  { int i = tid >> 5, r = tid & 31;
    ps[i][r] = proj[(size_t)(m0 + i) * PW + r]; }
  __syncthreads();
  float s[8];
  float bias = dtb[d0 + tid];
#pragma unroll
  for (int i = 0; i < 8; ++i) s[i] = bias;
#pragma unroll
  for (int r = 0; r < 32; ++r) {
    float wv = ws[tid][r];
#pragma unroll
    for (int i = 0; i < 8; ++i) s[i] = fmaf(ps[i][r], wv, s[i]);
  }
#pragma unroll
  for (int i = 0; i < 8; ++i) {
    float x = s[i];
    float sp = (x > 20.f) ? x : log1pf(__expf(x));
    delta[(size_t)(m0 + i) * DI + d0 + tid] = sp;
  }
}

// ---------------------------------------------------------------------------
// Chunked selective scan (complex, trapezoidal).
// lane = n (0..15) within 16-lane group; 16 (b,d) channels per block.
// PASS_B=false: per-chunk aggregates (prod alpha, U) -> agg buffers.
// PASS_B=true : recompute chunk-entry state from aggregates (<=15 complex
//               steps), rescan, emit ybuf = (y + D*xc) * silu(z).
// ---------------------------------------------------------------------------
template <bool PASS_B>
__global__ __launch_bounds__(256) void scan_pass(
    const float* __restrict__ proj, const float* __restrict__ delta,
    const float* __restrict__ xc, const float* __restrict__ xz,
    const float* __restrict__ A_log, const float* __restrict__ A_imag,
    const float* __restrict__ D_skip,
    float* __restrict__ aggAr, float* __restrict__ aggAi,
    float* __restrict__ aggUr, float* __restrict__ aggUi,
    float* __restrict__ ybuf) {
  const int tid = threadIdx.x;
  const int n = tid & 15;
  const int gch = blockIdx.x * 16 + (tid >> 4);  // (b,d) channel, 0..2047
  const int c = blockIdx.y;                      // chunk
  const int b = gch >> 10, d = gch & 1023;
  const float Ar = -__expf(A_log[d * 16 + n]);
  const float Ai = A_imag[d * 16 + n];
  const int t0 = c * CL;
  const int mb = b * L;
  const int lane = blockIdx.x * 256 + tid;       // flat (b,d,n) lane

  float Bxpr = 0.f, Bxpi = 0.f;
  if (t0 > 0) {  // Bx_prev for the first step of this chunk
    int mp = mb + t0 - 1;
    float xp = xc[(size_t)mp * DI + d];
    Bxpr = proj[(size_t)mp * PW + 32 + n] * xp;
    Bxpi = proj[(size_t)mp * PW + 48 + n] * xp;
  }
  float hr = 0.f, hi = 0.f, Aar = 1.f, Aai = 0.f, Dsk = 0.f;
  if (PASS_B) {
    // chunk-entry state: fold aggregates of chunks 0..c-1 (cheap: <=15 steps)
    for (int cc = 0; cc < c; ++cc) {
      int idx = cc * NLANES + lane;
      float ar = aggAr[idx], ai = aggAi[idx];
      float nr = ar * hr - ai * hi + aggUr[idx];
      float ni = ar * hi + ai * hr + aggUi[idx];
      hr = nr; hi = ni;
    }
    Dsk = D_skip[d];
  }

#pragma unroll 2
  for (int t = t0; t < t0 + CL; ++t) {
    const int m = mb + t;
    const float* row = proj + (size_t)m * PW;
    float Br = row[32 + n], Bi = row[48 + n];
    float dlt = delta[(size_t)m * DI + d];
    float xt = xc[(size_t)m * DI + d];
    float lam = row[96];                  // pre-sigmoided in proj_k
    float ear = __expf(dlt * Ar);
    float sn, cs; __sincosf(dlt * Ai, &sn, &cs);
    float ar = ear * cs, ai = ear * sn;
    float Bxr = Br * xt, Bxi = Bi * xt;
    float bsc = (1.f - lam) * dlt, g = lam * dlt;
    float ur = bsc * (ar * Bxpr - ai * Bxpi) + g * Bxr;
    float ui = bsc * (ar * Bxpi + ai * Bxpr) + g * Bxi;
    float nhr = ar * hr - ai * hi + ur;
    float nhi = ar * hi + ai * hr + ui;
    hr = nhr; hi = nhi;
    if (!PASS_B) {
      float nAr = Aar * ar - Aai * ai, nAi = Aar * ai + Aai * ar;
      Aar = nAr; Aai = nAi;
    }
    Bxpr = Bxr; Bxpi = Bxi;
    if (PASS_B) {
      float Cr = row[64 + n], Ci = row[80 + n];
      float yc = hr * Cr + hi * Ci;           // Re(h * conj(C))
      yc += __shfl_xor(yc, 1);
      yc += __shfl_xor(yc, 2);
      yc += __shfl_xor(yc, 4);
      yc += __shfl_xor(yc, 8);
      if (n == 0) {
        float y = yc + Dsk * xt;
        float zt = xz[(size_t)m * (2 * DI) + DI + d];
        ybuf[(size_t)m * DI + d] = y * (zt * sigmoidf_(zt));
      }
    }
  }
  if (!PASS_B) {
    int idx = c * NLANES + lane;
    aggAr[idx] = Aar; aggAi[idx] = Aai; aggUr[idx] = hr; aggUi[idx] = hi;
  }
}

extern "C" void kernel_launch(void* const* d_in, const int* in_sizes, int n_in,
                              void* d_out, int out_size, void* d_ws, size_t ws_size,
                              hipStream_t stream) {
  const float* x        = (const float*)d_in[0];
  const float* in_proj  = (const float*)d_in[1];
  const float* conv_w   = (const float*)d_in[2];
  const float* conv_b   = (const float*)d_in[3];
  const float* x_proj_w = (const float*)d_in[4];
  const float* dt_w     = (const float*)d_in[5];
  const float* dt_b     = (const float*)d_in[6];
  const float* A_log    = (const float*)d_in[7];
  const float* A_imag   = (const float*)d_in[8];
  const float* D_skip   = (const float*)d_in[9];
  const float* out_proj = (const float*)d_in[10];
  float* out = (float*)d_out;

  float* ws = (float*)d_ws;
  float* xz    = ws; ws += (size_t)ML * 2 * DI;   // 16.8 MB
  float* xc    = ws; ws += (size_t)ML * DI;       //  8.4 MB
  float* proj  = ws; ws += (size_t)ML * PW;       //  0.8 MB
  float* delta = ws; ws += (size_t)ML * DI;       //  8.4 MB
  float* ybuf  = ws; ws += (size_t)ML * DI;       //  8.4 MB
  float* aggAr = ws; ws += (size_t)NCHUNK * NLANES;  // 2.1 MB each
  float* aggAi = ws; ws += (size_t)NCHUNK * NLANES;
  float* aggUr = ws; ws += (size_t)NCHUNK * NLANES;
  float* aggUi = ws; ws += (size_t)NCHUNK * NLANES;  // total ~51.3 MB

  gemm_bt_f32<<<dim3(2 * DI / 64, ML / 64), 256, 0, stream>>>(x, in_proj, xz, ML, 2 * DI, DM);
  conv_silu_k<<<ML * DI / 256, 256, 0, stream>>>(xz, conv_w, conv_b, xc);
  proj_k<<<ML / 4, 128, 0, stream>>>(xc, x_proj_w, proj);
  delta_k<<<dim3(DI / 256, ML / 8), 256, 0, stream>>>(proj, dt_w, dt_b, delta);
  scan_pass<false><<<dim3(128, NCHUNK), 256, 0, stream>>>(
      proj, delta, xc, xz, A_log, A_imag, D_skip,
      aggAr, aggAi, aggUr, aggUi, nullptr);
  scan_pass<true><<<dim3(128, NCHUNK), 256, 0, stream>>>(
      proj, delta, xc, xz, A_log, A_imag, D_skip,
      aggAr, aggAi, aggUr, aggUi, ybuf);
  gemm_bt_f32<<<dim3(DM / 64, ML / 64), 256, 0, stream>>>(ybuf, out_proj, out, ML, DM, DI);
}

// Round 3
// 228.231 us; speedup vs baseline: 1.6237x; 1.3435x over previous
//
#include <hip/hip_runtime.h>

// Mamba block forward. Round 3: packed scan inputs + bf16 MFMA GEMMs.
constexpr int B  = 2, L = 1024, DM = 512, DI = 1024, NST = 16, PW = 97;
constexpr int ML = B * L;                   // 2048 rows
constexpr int NCHUNK = 16, CL = L / NCHUNK; // 16 chunks x 64 steps
constexpr int NLANES = B * DI * NST;        // 32768 scan lanes

#define DEV_INLINE __device__ __forceinline__

typedef __attribute__((ext_vector_type(8))) short bf16x8;   // 8 bf16 (4 VGPRs)
typedef __attribute__((ext_vector_type(4))) float f32x4;    // 4 fp32 acc

DEV_INLINE float sigmoidf_(float x) { return 1.f / (1.f + __expf(-x)); }
DEV_INLINE unsigned short f2bf(float f) {
  unsigned int u = __float_as_uint(f);
  return (unsigned short)((u + 0x7FFFu + ((u >> 16) & 1u)) >> 16);  // RNE
}

// ---------------------------------------------------------------------------
// f32 -> bf16 convert (vectorized: float4 in, 4x bf16 out)
// ---------------------------------------------------------------------------
__global__ __launch_bounds__(256) void cvt_k(const float* __restrict__ in,
                                             unsigned short* __restrict__ out, int n4) {
  int i = blockIdx.x * 256 + threadIdx.x;
  if (i < n4) {
    float4 v = ((const float4*)in)[i];
    ushort4 o = make_ushort4(f2bf(v.x), f2bf(v.y), f2bf(v.z), f2bf(v.w));
    ((ushort4*)out)[i] = o;
  }
}

// ---------------------------------------------------------------------------
// bf16 MFMA GEMM: C(M,N) f32 = A(M,K)bf16 @ W(N,K)bf16^T.
// 128x128 tile, BK=64, 4 waves (2x2 quadrants of 64x64), 16x16x32 MFMA.
// Reg-staged LDS with XOR swizzle (byte ^= (row&7)<<4) for conflict-free
// ds_read_b128 fragment reads.
// ---------------------------------------------------------------------------
DEV_INLINE int swz(int row, int kb) { return (row << 7) + (kb ^ ((row & 7) << 4)); }

__global__ __launch_bounds__(256) void gemm_bf16(
    const short* __restrict__ A, const short* __restrict__ W,
    float* __restrict__ C, int M, int N, int K) {
  __shared__ char ldsb[32768];                 // A tile [0,16K), W tile [16K,32K)
  const int tid = threadIdx.x;
  const int lane = tid & 63, wv = tid >> 6;
  const int wm = wv >> 1, wn = wv & 1;
  const int bm = blockIdx.y * 128, bn = blockIdx.x * 128;

  f32x4 acc[4][4];
#pragma unroll
  for (int mi = 0; mi < 4; ++mi)
#pragma unroll
    for (int ni = 0; ni < 4; ++ni) acc[mi][ni] = (f32x4){0.f, 0.f, 0.f, 0.f};

  for (int k0 = 0; k0 < K; k0 += 64) {
    // stage: 128 rows x 64 bf16 (128B/row) per tile; 256 thr x 16B x 4 iters
#pragma unroll
    for (int i = 0; i < 4; ++i) {
      int off = i * 4096 + tid * 16;
      int row = off >> 7, kb = off & 127;
      bf16x8 va = *(const bf16x8*)(A + (size_t)(bm + row) * K + k0 + (kb >> 1));
      bf16x8 vw = *(const bf16x8*)(W + (size_t)(bn + row) * K + k0 + (kb >> 1));
      *(bf16x8*)(ldsb + swz(row, kb)) = va;
      *(bf16x8*)(ldsb + 16384 + swz(row, kb)) = vw;
    }
    __syncthreads();
#pragma unroll
    for (int ks = 0; ks < 2; ++ks) {
      bf16x8 af[4], bfr[4];
      const int kb = ks * 64 + ((lane >> 4) << 4);
#pragma unroll
      for (int mi = 0; mi < 4; ++mi) {
        int row = wm * 64 + mi * 16 + (lane & 15);
        af[mi] = *(const bf16x8*)(ldsb + swz(row, kb));
      }
#pragma unroll
      for (int ni = 0; ni < 4; ++ni) {
        int row = wn * 64 + ni * 16 + (lane & 15);
        bfr[ni] = *(const bf16x8*)(ldsb + 16384 + swz(row, kb));
      }
#pragma unroll
      for (int mi = 0; mi < 4; ++mi)
#pragma unroll
        for (int ni = 0; ni < 4; ++ni)
          acc[mi][ni] = __builtin_amdgcn_mfma_f32_16x16x32_bf16(
              af[mi], bfr[ni], acc[mi][ni], 0, 0, 0);
    }
    __syncthreads();
  }
  // epilogue: C/D layout col=lane&15, row=(lane>>4)*4+reg
#pragma unroll
  for (int mi = 0; mi < 4; ++mi)
#pragma unroll
    for (int ni = 0; ni < 4; ++ni) {
      int col = bn + wn * 64 + ni * 16 + (lane & 15);
      int row0 = bm + wm * 64 + mi * 16 + ((lane >> 4) << 2);
#pragma unroll
      for (int j = 0; j < 4; ++j)
        C[(size_t)(row0 + j) * N + col] = acc[mi][ni][j];
    }
}

// ---------------------------------------------------------------------------
// causal depthwise conv (K=3) + bias + SiLU -> xc; also silu(z) -> sz
// ---------------------------------------------------------------------------
__global__ __launch_bounds__(256) void conv_silu_k(
    const float* __restrict__ xz, const float* __restrict__ cw,
    const float* __restrict__ cb, float* __restrict__ xc, float* __restrict__ sz) {
  int idx = blockIdx.x * 256 + threadIdx.x;   // (m,d)
  int m = idx >> 10, d = idx & 1023;
  int t = m & (L - 1);
  float w0 = cw[d * 3 + 0], w1 = cw[d * 3 + 1], w2 = cw[d * 3 + 2];
  float v = cb[d];
  v = fmaf(xz[(size_t)m * (2 * DI) + d], w2, v);
  if (t >= 1) v = fmaf(xz[(size_t)(m - 1) * (2 * DI) + d], w1, v);
  if (t >= 2) v = fmaf(xz[(size_t)(m - 2) * (2 * DI) + d], w0, v);
  xc[idx] = v * sigmoidf_(v);
  float z = xz[(size_t)m * (2 * DI) + DI + d];
  sz[idx] = z * sigmoidf_(z);
}

// ---------------------------------------------------------------------------
// x_proj: (ML,1024) x (97,1024)^T, scattered into scan-friendly layouts:
//   dtp[m*32+r] (delta_k input), bcf[m*32+{2i,2i+1}]=B_{re,im},
//   ccf likewise for C, lamv[m]=sigmoid(lam).
// ---------------------------------------------------------------------------
__global__ __launch_bounds__(128) void proj_k(
    const float* __restrict__ xc, const float* __restrict__ xw,
    float* __restrict__ dtp, float* __restrict__ bcf,
    float* __restrict__ ccf, float* __restrict__ lamv) {
  __shared__ float xs[4][DI];
  int m0 = blockIdx.x * 4;
  for (int i = threadIdx.x; i < 4 * DI; i += 128)
    xs[i >> 10][i & 1023] = xc[(size_t)m0 * DI + i];
  __syncthreads();
  int nn = threadIdx.x;
  if (nn >= PW) return;
  const float* wr = xw + (size_t)nn * DI;
  float s0 = 0.f, s1 = 0.f, s2 = 0.f, s3 = 0.f;
#pragma unroll 4
  for (int k = 0; k < DI; k += 4) {
    float4 w4 = *(const float4*)(wr + k);
    s0 = fmaf(xs[0][k], w4.x, s0); s0 = fmaf(xs[0][k + 1], w4.y, s0);
    s0 = fmaf(xs[0][k + 2], w4.z, s0); s0 = fmaf(xs[0][k + 3], w4.w, s0);
    s1 = fmaf(xs[1][k], w4.x, s1); s1 = fmaf(xs[1][k + 1], w4.y, s1);
    s1 = fmaf(xs[1][k + 2], w4.z, s1); s1 = fmaf(xs[1][k + 3], w4.w, s1);
    s2 = fmaf(xs[2][k], w4.x, s2); s2 = fmaf(xs[2][k + 1], w4.y, s2);
    s2 = fmaf(xs[2][k + 2], w4.z, s2); s2 = fmaf(xs[2][k + 3], w4.w, s2);
    s3 = fmaf(xs[3][k], w4.x, s3); s3 = fmaf(xs[3][k + 1], w4.y, s3);
    s3 = fmaf(xs[3][k + 2], w4.z, s3); s3 = fmaf(xs[3][k + 3], w4.w, s3);
  }
  float sv[4] = {s0, s1, s2, s3};
#pragma unroll
  for (int r = 0; r < 4; ++r) {
    int m = m0 + r;
    float s = sv[r];
    if (nn < 32)        dtp[m * 32 + nn] = s;
    else if (nn < 48)   bcf[m * 32 + 2 * (nn - 32)] = s;
    else if (nn < 64)   bcf[m * 32 + 2 * (nn - 48) + 1] = s;
    else if (nn < 80)   ccf[m * 32 + 2 * (nn - 64)] = s;
    else if (nn < 96)   ccf[m * 32 + 2 * (nn - 80) + 1] = s;
    else                lamv[m] = sigmoidf_(s);
  }
}

// ---------------------------------------------------------------------------
// delta = softplus(dtp @ dt_w^T + dt_b); emit packed float4 {dlt, xt, bsc, g}
// ---------------------------------------------------------------------------
__global__ __launch_bounds__(256) void delta_k(
    const float* __restrict__ dtp, const float* __restrict__ dtw,
    const float* __restrict__ dtb, const float* __restrict__ xc,
    const float* __restrict__ lamv, float4* __restrict__ dxbg) {
  __shared__ float ws[256][33];
  __shared__ float ps[8][32];
  const int tid = threadIdx.x;
  const int d0 = blockIdx.x * 256;
  const int m0 = blockIdx.y * 8;
#pragma unroll
  for (int j = 0; j < 8; ++j) {
    int flat = tid * 4 + j * 1024;
    int r = flat >> 5, c = flat & 31;
    float4 v = *(const float4*)(dtw + (size_t)d0 * 32 + flat);
    ws[r][c] = v.x; ws[r][c + 1] = v.y; ws[r][c + 2] = v.z; ws[r][c + 3] = v.w;
  }
  { int i = tid >> 5, r = tid & 31;
    ps[i][r] = dtp[(size_t)(m0 + i) * 32 + r]; }
  __syncthreads();
  float s[8];
  float bias = dtb[d0 + tid];
#pragma unroll
  for (int i = 0; i < 8; ++i) s[i] = bias;
#pragma unroll
  for (int r = 0; r < 32; ++r) {
    float wv = ws[tid][r];
#pragma unroll
    for (int i = 0; i < 8; ++i) s[i] = fmaf(ps[i][r], wv, s[i]);
  }
#pragma unroll
  for (int i = 0; i < 8; ++i) {
    float x = s[i];
    float dlt = (x > 20.f) ? x : log1pf(__expf(x));
    int m = m0 + i;
    float xt = xc[(size_t)m * DI + d0 + tid];
    float lam = lamv[m];
    dxbg[(size_t)m * DI + d0 + tid] = make_float4(dlt, xt, (1.f - lam) * dlt, lam * dlt);
  }
}

// ---------------------------------------------------------------------------
// Chunked selective scan (complex, trapezoidal), packed inputs.
// lane = n (0..15); 16 (b,d) channels per block (same b).
// ---------------------------------------------------------------------------
template <bool PASS_B>
__global__ __launch_bounds__(256) void scan_pass(
    const float4* __restrict__ dxbg, const float2* __restrict__ bc,
    const float2* __restrict__ cc, const float* __restrict__ sz,
    const float* __restrict__ A_log, const float* __restrict__ A_imag,
    const float* __restrict__ D_skip,
    float2* __restrict__ aggA, float2* __restrict__ aggU,
    unsigned short* __restrict__ ybuf) {
  const int tid = threadIdx.x;
  const int n = tid & 15;
  const int gch = blockIdx.x * 16 + (tid >> 4);
  const int c = blockIdx.y;
  const int b = gch >> 10, d = gch & 1023;
  const float Ar = -__expf(A_log[d * 16 + n]);
  const float Ai = A_imag[d * 16 + n];
  const int t0 = c * CL, mb = b * L;
  const int lane = blockIdx.x * 256 + tid;

  float Bxpr = 0.f, Bxpi = 0.f;
  if (t0 > 0) {
    int mp = mb + t0 - 1;
    float xp = dxbg[(size_t)mp * DI + d].y;
    float2 bp = bc[mp * 16 + n];
    Bxpr = bp.x * xp; Bxpi = bp.y * xp;
  }
  float hr = 0.f, hi = 0.f, Aar = 1.f, Aai = 0.f, Dsk = 0.f;
  if (PASS_B) {
    for (int q = 0; q < c; ++q) {       // fold prior chunk aggregates
      int idx = q * NLANES + lane;
      float2 a = aggA[idx], u = aggU[idx];
      float nr = a.x * hr - a.y * hi + u.x;
      float ni = a.x * hi + a.y * hr + u.y;
      hr = nr; hi = ni;
    }
    Dsk = D_skip[d];
  }

  size_t ix = (size_t)(mb + t0) * DI + d;
  int ibc = (mb + t0) * 16 + n;
#pragma unroll 4
  for (int t = 0; t < CL; ++t, ix += DI, ibc += 16) {
    float4 q = dxbg[ix];                 // dlt, xt, bsc, g
    float2 bv = bc[ibc];
    float ear = __expf(q.x * Ar);
    float sn, cs; __sincosf(q.x * Ai, &sn, &cs);
    float ar = ear * cs, ai = ear * sn;
    float Bxr = bv.x * q.y, Bxi = bv.y * q.y;
    float ur = q.z * (ar * Bxpr - ai * Bxpi) + q.w * Bxr;
    float ui = q.z * (ar * Bxpi + ai * Bxpr) + q.w * Bxi;
    float nhr = ar * hr - ai * hi + ur;
    float nhi = ar * hi + ai * hr + ui;
    hr = nhr; hi = nhi;
    Bxpr = Bxr; Bxpi = Bxi;
    if (!PASS_B) {
      float nAr = Aar * ar - Aai * ai, nAi = Aar * ai + Aai * ar;
      Aar = nAr; Aai = nAi;
    } else {
      float2 cv = cc[ibc];
      float yc = hr * cv.x + hi * cv.y;  // Re(h * conj(C))
      yc += __shfl_xor(yc, 1);
      yc += __shfl_xor(yc, 2);
      yc += __shfl_xor(yc, 4);
      yc += __shfl_xor(yc, 8);
      if (n == 0) {
        float y = yc + Dsk * q.y;
        ybuf[ix] = f2bf(y * sz[ix]);
      }
    }
  }
  if (!PASS_B) {
    int idx = c * NLANES + lane;
    aggA[idx] = make_float2(Aar, Aai);
    aggU[idx] = make_float2(hr, hi);
  }
}

extern "C" void kernel_launch(void* const* d_in, const int* in_sizes, int n_in,
                              void* d_out, int out_size, void* d_ws, size_t ws_size,
                              hipStream_t stream) {
  const float* x        = (const float*)d_in[0];
  const float* in_proj  = (const float*)d_in[1];
  const float* conv_w   = (const float*)d_in[2];
  const float* conv_b   = (const float*)d_in[3];
  const float* x_proj_w = (const float*)d_in[4];
  const float* dt_w     = (const float*)d_in[5];
  const float* dt_b     = (const float*)d_in[6];
  const float* A_log    = (const float*)d_in[7];
  const float* A_imag   = (const float*)d_in[8];
  const float* D_skip   = (const float*)d_in[9];
  const float* out_proj = (const float*)d_in[10];
  float* out = (float*)d_out;

  float* ws = (float*)d_ws;
  float*  xz    = ws; ws += (size_t)ML * 2 * DI;        // 16.8 MB
  float*  xc    = ws; ws += (size_t)ML * DI;            //  8.4 MB
  float*  sz    = ws; ws += (size_t)ML * DI;            //  8.4 MB
  float4* dxbg  = (float4*)ws; ws += (size_t)ML * DI * 4; // 33.5 MB
  float*  dtp   = ws; ws += (size_t)ML * 32;
  float*  bcf   = ws; ws += (size_t)ML * 32;
  float*  ccf   = ws; ws += (size_t)ML * 32;
  float*  lamv  = ws; ws += ML;
  float2* aggA  = (float2*)ws; ws += (size_t)NCHUNK * NLANES * 2;
  float2* aggU  = (float2*)ws; ws += (size_t)NCHUNK * NLANES * 2;
  unsigned short* xb   = (unsigned short*)ws; ws += (size_t)ML * DM / 2;
  unsigned short* wb1  = (unsigned short*)ws; ws += (size_t)(2 * DI) * DM / 2;
  unsigned short* wb2  = (unsigned short*)ws; ws += (size_t)DM * DI / 2;
  unsigned short* ybuf = (unsigned short*)ws; ws += (size_t)ML * DI / 2;

  cvt_k<<<(ML * DM / 4 + 255) / 256, 256, 0, stream>>>(x, xb, ML * DM / 4);
  cvt_k<<<(2 * DI * DM / 4 + 255) / 256, 256, 0, stream>>>(in_proj, wb1, 2 * DI * DM / 4);
  cvt_k<<<(DM * DI / 4 + 255) / 256, 256, 0, stream>>>(out_proj, wb2, DM * DI / 4);

  gemm_bf16<<<dim3(2 * DI / 128, ML / 128), 256, 0, stream>>>(
      (const short*)xb, (const short*)wb1, xz, ML, 2 * DI, DM);
  conv_silu_k<<<ML * DI / 256, 256, 0, stream>>>(xz, conv_w, conv_b, xc, sz);
  proj_k<<<ML / 4, 128, 0, stream>>>(xc, x_proj_w, dtp, bcf, ccf, lamv);
  delta_k<<<dim3(DI / 256, ML / 8), 256, 0, stream>>>(dtp, dt_w, dt_b, xc, lamv, dxbg);
  scan_pass<false><<<dim3(128, NCHUNK), 256, 0, stream>>>(
      dxbg, (const float2*)bcf, (const float2*)ccf, sz, A_log, A_imag, D_skip,
      aggA, aggU, nullptr);
  scan_pass<true><<<dim3(128, NCHUNK), 256, 0, stream>>>(
      dxbg, (const float2*)bcf, (const float2*)ccf, sz, A_log, A_imag, D_skip,
      aggA, aggU, ybuf);
  gemm_bf16<<<dim3(DM / 128, ML / 128), 256, 0, stream>>>(
      (const short*)ybuf, (const short*)wb2, out, ML, DM, DI);
}

// Round 4
// 222.793 us; speedup vs baseline: 1.6633x; 1.0244x over previous
//
#include <hip/hip_runtime.h>

// Mamba block forward. Round 4: scan instruction diet (bcc float4, prescaled
// trans args, log-space chunk aggregate, combine kernel, prefetch pipeline).
constexpr int B  = 2, L = 1024, DM = 512, DI = 1024, NST = 16, PW = 97;
constexpr int ML = B * L;                   // 2048 rows
constexpr int NCHUNK = 16, CL = L / NCHUNK; // 16 chunks x 64 steps
constexpr int NLANES = B * DI * NST;        // 32768 scan lanes

#define DEV_INLINE __device__ __forceinline__

typedef __attribute__((ext_vector_type(8))) short bf16x8;   // 8 bf16 (4 VGPRs)
typedef __attribute__((ext_vector_type(4))) float f32x4;    // 4 fp32 acc

DEV_INLINE float sigmoidf_(float x) { return 1.f / (1.f + __expf(-x)); }
DEV_INLINE unsigned short f2bf(float f) {
  unsigned int u = __float_as_uint(f);
  return (unsigned short)((u + 0x7FFFu + ((u >> 16) & 1u)) >> 16);  // RNE
}

#if __has_builtin(__builtin_amdgcn_exp2f)
#define EXP2F(x) __builtin_amdgcn_exp2f(x)
#else
#define EXP2F(x) exp2f(x)
#endif
#if __has_builtin(__builtin_amdgcn_sinf)
#define SINR(x) __builtin_amdgcn_sinf(x)   // sin(2*pi*x), x in revolutions
#define COSR(x) __builtin_amdgcn_cosf(x)
#else
#define SINR(x) __sinf((x) * 6.2831853f)
#define COSR(x) __cosf((x) * 6.2831853f)
#endif

// ---------------------------------------------------------------------------
// f32 -> bf16 convert, 3 segments in one launch (x, in_proj_w, out_proj_w)
// ---------------------------------------------------------------------------
__global__ __launch_bounds__(256) void cvt3_k(
    const float* __restrict__ i0, unsigned short* __restrict__ o0, int n0,
    const float* __restrict__ i1, unsigned short* __restrict__ o1, int n1,
    const float* __restrict__ i2, unsigned short* __restrict__ o2, int n2) {
  int i = blockIdx.x * 256 + threadIdx.x;   // in float4 units
  const float* in; unsigned short* out; int off;
  if (i < n0)              { in = i0; out = o0; off = i; }
  else if (i < n0 + n1)    { in = i1; out = o1; off = i - n0; }
  else if (i < n0 + n1 + n2) { in = i2; out = o2; off = i - n0 - n1; }
  else return;
  float4 v = ((const float4*)in)[off];
  ((ushort4*)out)[off] = make_ushort4(f2bf(v.x), f2bf(v.y), f2bf(v.z), f2bf(v.w));
}

// ---------------------------------------------------------------------------
// bf16 MFMA GEMM: C(M,N) f32 = A(M,K)bf16 @ W(N,K)bf16^T.
// 128x128 tile, BK=64, 4 waves, 16x16x32 MFMA, XOR-swizzled LDS.
// ---------------------------------------------------------------------------
DEV_INLINE int swz(int row, int kb) { return (row << 7) + (kb ^ ((row & 7) << 4)); }

__global__ __launch_bounds__(256) void gemm_bf16(
    const short* __restrict__ A, const short* __restrict__ W,
    float* __restrict__ C, int M, int N, int K) {
  __shared__ char ldsb[32768];
  const int tid = threadIdx.x;
  const int lane = tid & 63, wv = tid >> 6;
  const int wm = wv >> 1, wn = wv & 1;
  const int bm = blockIdx.y * 128, bn = blockIdx.x * 128;

  f32x4 acc[4][4];
#pragma unroll
  for (int mi = 0; mi < 4; ++mi)
#pragma unroll
    for (int ni = 0; ni < 4; ++ni) acc[mi][ni] = (f32x4){0.f, 0.f, 0.f, 0.f};

  for (int k0 = 0; k0 < K; k0 += 64) {
#pragma unroll
    for (int i = 0; i < 4; ++i) {
      int off = i * 4096 + tid * 16;
      int row = off >> 7, kb = off & 127;
      bf16x8 va = *(const bf16x8*)(A + (size_t)(bm + row) * K + k0 + (kb >> 1));
      bf16x8 vw = *(const bf16x8*)(W + (size_t)(bn + row) * K + k0 + (kb >> 1));
      *(bf16x8*)(ldsb + swz(row, kb)) = va;
      *(bf16x8*)(ldsb + 16384 + swz(row, kb)) = vw;
    }
    __syncthreads();
#pragma unroll
    for (int ks = 0; ks < 2; ++ks) {
      bf16x8 af[4], bfr[4];
      const int kb = ks * 64 + ((lane >> 4) << 4);
#pragma unroll
      for (int mi = 0; mi < 4; ++mi) {
        int row = wm * 64 + mi * 16 + (lane & 15);
        af[mi] = *(const bf16x8*)(ldsb + swz(row, kb));
      }
#pragma unroll
      for (int ni = 0; ni < 4; ++ni) {
        int row = wn * 64 + ni * 16 + (lane & 15);
        bfr[ni] = *(const bf16x8*)(ldsb + 16384 + swz(row, kb));
      }
#pragma unroll
      for (int mi = 0; mi < 4; ++mi)
#pragma unroll
        for (int ni = 0; ni < 4; ++ni)
          acc[mi][ni] = __builtin_amdgcn_mfma_f32_16x16x32_bf16(
              af[mi], bfr[ni], acc[mi][ni], 0, 0, 0);
    }
    __syncthreads();
  }
#pragma unroll
  for (int mi = 0; mi < 4; ++mi)
#pragma unroll
    for (int ni = 0; ni < 4; ++ni) {
      int col = bn + wn * 64 + ni * 16 + (lane & 15);
      int row0 = bm + wm * 64 + mi * 16 + ((lane >> 4) << 2);
#pragma unroll
      for (int j = 0; j < 4; ++j)
        C[(size_t)(row0 + j) * N + col] = acc[mi][ni][j];
    }
}

// ---------------------------------------------------------------------------
// causal depthwise conv (K=3) + bias + SiLU -> xc; also silu(z) -> sz
// ---------------------------------------------------------------------------
__global__ __launch_bounds__(256) void conv_silu_k(
    const float* __restrict__ xz, const float* __restrict__ cw,
    const float* __restrict__ cb, float* __restrict__ xc, float* __restrict__ sz) {
  int idx = blockIdx.x * 256 + threadIdx.x;   // (m,d)
  int m = idx >> 10, d = idx & 1023;
  int t = m & (L - 1);
  float w0 = cw[d * 3 + 0], w1 = cw[d * 3 + 1], w2 = cw[d * 3 + 2];
  float v = cb[d];
  v = fmaf(xz[(size_t)m * (2 * DI) + d], w2, v);
  if (t >= 1) v = fmaf(xz[(size_t)(m - 1) * (2 * DI) + d], w1, v);
  if (t >= 2) v = fmaf(xz[(size_t)(m - 2) * (2 * DI) + d], w0, v);
  xc[idx] = v * sigmoidf_(v);
  float z = xz[(size_t)m * (2 * DI) + DI + d];
  sz[idx] = z * sigmoidf_(z);
}

// ---------------------------------------------------------------------------
// x_proj: (ML,1024) x (97,1024)^T, scattered into scan layouts:
//   dtp[m*32+r], bcc[m*16+j] = {Br,Bi,Cr,Ci} (component writes), lamv[m].
// 2 rows per block for wave count.
// ---------------------------------------------------------------------------
__global__ __launch_bounds__(128) void proj_k(
    const float* __restrict__ xc, const float* __restrict__ xw,
    float* __restrict__ dtp, float* __restrict__ bccf, float* __restrict__ lamv) {
  __shared__ float xs[2][DI];
  int m0 = blockIdx.x * 2;
  for (int i = threadIdx.x; i < 2 * DI; i += 128)
    xs[i >> 10][i & 1023] = xc[(size_t)m0 * DI + i];
  __syncthreads();
  int nn = threadIdx.x;
  if (nn >= PW) return;
  const float* wr = xw + (size_t)nn * DI;
  float s0 = 0.f, s1 = 0.f;
#pragma unroll 8
  for (int k = 0; k < DI; k += 4) {
    float4 w4 = *(const float4*)(wr + k);
    s0 = fmaf(xs[0][k], w4.x, s0); s0 = fmaf(xs[0][k + 1], w4.y, s0);
    s0 = fmaf(xs[0][k + 2], w4.z, s0); s0 = fmaf(xs[0][k + 3], w4.w, s0);
    s1 = fmaf(xs[1][k], w4.x, s1); s1 = fmaf(xs[1][k + 1], w4.y, s1);
    s1 = fmaf(xs[1][k + 2], w4.z, s1); s1 = fmaf(xs[1][k + 3], w4.w, s1);
  }
  float sv[2] = {s0, s1};
#pragma unroll
  for (int r = 0; r < 2; ++r) {
    int m = m0 + r;
    float s = sv[r];
    if (nn < 32)        dtp[m * 32 + nn] = s;
    else if (nn < 48)   bccf[(m * 16 + nn - 32) * 4 + 0] = s;
    else if (nn < 64)   bccf[(m * 16 + nn - 48) * 4 + 1] = s;
    else if (nn < 80)   bccf[(m * 16 + nn - 64) * 4 + 2] = s;
    else if (nn < 96)   bccf[(m * 16 + nn - 80) * 4 + 3] = s;
    else                lamv[m] = sigmoidf_(s);
  }
}

// ---------------------------------------------------------------------------
// delta = softplus(dtp @ dt_w^T + dt_b); emit packed float4 {dlt, xt, bsc, g}
// ---------------------------------------------------------------------------
__global__ __launch_bounds__(256) void delta_k(
    const float* __restrict__ dtp, const float* __restrict__ dtw,
    const float* __restrict__ dtb, const float* __restrict__ xc,
    const float* __restrict__ lamv, float4* __restrict__ dxbg) {
  __shared__ float ws[256][33];
  __shared__ float ps[8][32];
  const int tid = threadIdx.x;
  const int d0 = blockIdx.x * 256;
  const int m0 = blockIdx.y * 8;
#pragma unroll
  for (int j = 0; j < 8; ++j) {
    int flat = tid * 4 + j * 1024;
    int r = flat >> 5, c = flat & 31;
    float4 v = *(const float4*)(dtw + (size_t)d0 * 32 + flat);
    ws[r][c] = v.x; ws[r][c + 1] = v.y; ws[r][c + 2] = v.z; ws[r][c + 3] = v.w;
  }
  { int i = tid >> 5, r = tid & 31;
    ps[i][r] = dtp[(size_t)(m0 + i) * 32 + r]; }
  __syncthreads();
  float s[8];
  float bias = dtb[d0 + tid];
#pragma unroll
  for (int i = 0; i < 8; ++i) s[i] = bias;
#pragma unroll
  for (int r = 0; r < 32; ++r) {
    float wv = ws[tid][r];
#pragma unroll
    for (int i = 0; i < 8; ++i) s[i] = fmaf(ps[i][r], wv, s[i]);
  }
#pragma unroll
  for (int i = 0; i < 8; ++i) {
    float x = s[i];
    float dlt = (x > 20.f) ? x : log1pf(__expf(x));
    int m = m0 + i;
    float xt = xc[(size_t)m * DI + d0 + tid];
    float lam = lamv[m];
    dxbg[(size_t)m * DI + d0 + tid] = make_float4(dlt, xt, (1.f - lam) * dlt, lam * dlt);
  }
}

// ---------------------------------------------------------------------------
// Chunked selective scan. lane = n (0..15); 16 (b,d) channels per block.
// PASS_A: agg (prod alpha via log-space sum, U) for chunks 0..14.
// combine: chunk-entry prefix states hp.
// PASS_B: load hp, rescan, emit ybuf bf16.
// ---------------------------------------------------------------------------
template <bool PASS_B>
__global__ __launch_bounds__(256) void scan_pass(
    const float4* __restrict__ dxbg, const float4* __restrict__ bcc,
    const float* __restrict__ sz,
    const float* __restrict__ A_log, const float* __restrict__ A_imag,
    const float* __restrict__ D_skip,
    float2* __restrict__ aggA, float2* __restrict__ aggU,
    const float2* __restrict__ hp, unsigned short* __restrict__ ybuf) {
  const int tid = threadIdx.x;
  const int n = tid & 15;
  const int gch = blockIdx.x * 16 + (tid >> 4);
  const int c = blockIdx.y;
  const int b = gch >> 10, d = gch & 1023;
  const int lane = blockIdx.x * 256 + tid;
  const float Ar = -__expf(A_log[d * 16 + n]);
  const float Arl = Ar * 1.44269504f;                 // * log2(e)
  const float Airv = A_imag[d * 16 + n] * 0.15915494f; // / (2*pi)
  const int t0 = c * CL, mb = b * L;
  const unsigned ix0 = (unsigned)(mb + t0) * DI + d;

  float Bxpr = 0.f, Bxpi = 0.f;
  if (c > 0) {
    float xp = dxbg[ix0 - DI].y;
    float4 bp = bcc[(mb + t0 - 1) * 16 + n];
    Bxpr = bp.x * xp; Bxpi = bp.y * xp;
  }
  float hr = 0.f, hi = 0.f, S = 0.f, Dsk = 0.f;
  if (PASS_B) {
    float2 h0 = hp[c * NLANES + lane];
    hr = h0.x; hi = h0.y;
    Dsk = D_skip[d];
  }

  const float4* qp = dxbg + ix0;
  const float4* pp = bcc + (mb + t0) * 16 + n;
  float4 q = *qp, p = *pp;
#pragma unroll 4
  for (int t = 0; t < CL; ++t) {
    qp += DI; pp += 16;
    float4 qn = *qp;       // distance-1 prefetch (padded overread on last t)
    float4 pn = *pp;
    float ear = EXP2F(q.x * Arl);
    float rv = q.x * Airv;
    float sn = SINR(rv), cs = COSR(rv);
    float ar = ear * cs, ai = ear * sn;
    float Bxr = p.x * q.y, Bxi = p.y * q.y;
    float ur = q.z * (ar * Bxpr - ai * Bxpi) + q.w * Bxr;
    float ui = q.z * (ar * Bxpi + ai * Bxpr) + q.w * Bxi;
    float nhr = ar * hr - ai * hi + ur;
    float nhi = ar * hi + ai * hr + ui;
    hr = nhr; hi = nhi;
    Bxpr = Bxr; Bxpi = Bxi;
    if (!PASS_B) {
      S += q.x;                         // log-space aggregate of prod(alpha)
    } else {
      float yc = hr * p.z + hi * p.w;   // Re(h * conj(C))
      yc += __shfl_xor(yc, 1);
      yc += __shfl_xor(yc, 2);
      yc += __shfl_xor(yc, 4);
      yc += __shfl_xor(yc, 8);
      if (n == 0) {
        unsigned ixm = ix0 + ((unsigned)t << 10);
        float y = yc + Dsk * q.y;
        ybuf[ixm] = f2bf(y * sz[ixm]);
      }
    }
    q = qn; p = pn;
  }
  if (!PASS_B) {
    float earS = EXP2F(S * Arl);
    float rvS = S * Airv;
    float AaR = earS * COSR(rvS);
    float AaI = earS * SINR(rvS);
    int idx = c * NLANES + lane;
    aggA[idx] = make_float2(AaR, AaI);
    aggU[idx] = make_float2(hr, hi);
  }
}

// chunk-entry prefix states from aggregates (fully unrolled, loads prefetched)
__global__ __launch_bounds__(256) void scan_combine_k(
    const float2* __restrict__ aggA, const float2* __restrict__ aggU,
    float2* __restrict__ hp) {
  int gid = blockIdx.x * 256 + threadIdx.x;
  float2 a[NCHUNK - 1], u[NCHUNK - 1];
#pragma unroll
  for (int c = 0; c < NCHUNK - 1; ++c) {
    a[c] = aggA[c * NLANES + gid];
    u[c] = aggU[c * NLANES + gid];
  }
  float hr = 0.f, hi = 0.f;
#pragma unroll
  for (int c = 0; c < NCHUNK; ++c) {
    hp[c * NLANES + gid] = make_float2(hr, hi);
    if (c < NCHUNK - 1) {
      float nr = a[c].x * hr - a[c].y * hi + u[c].x;
      float ni = a[c].x * hi + a[c].y * hr + u[c].y;
      hr = nr; hi = ni;
    }
  }
}

extern "C" void kernel_launch(void* const* d_in, const int* in_sizes, int n_in,
                              void* d_out, int out_size, void* d_ws, size_t ws_size,
                              hipStream_t stream) {
  const float* x        = (const float*)d_in[0];
  const float* in_proj  = (const float*)d_in[1];
  const float* conv_w   = (const float*)d_in[2];
  const float* conv_b   = (const float*)d_in[3];
  const float* x_proj_w = (const float*)d_in[4];
  const float* dt_w     = (const float*)d_in[5];
  const float* dt_b     = (const float*)d_in[6];
  const float* A_log    = (const float*)d_in[7];
  const float* A_imag   = (const float*)d_in[8];
  const float* D_skip   = (const float*)d_in[9];
  const float* out_proj = (const float*)d_in[10];
  float* out = (float*)d_out;

  float* ws = (float*)d_ws;
  float*  xz    = ws; ws += (size_t)ML * 2 * DI;            // 16.8 MB
  float*  xc    = ws; ws += (size_t)ML * DI;                //  8.4 MB
  float*  sz    = ws; ws += (size_t)ML * DI;                //  8.4 MB
  float4* dxbg  = (float4*)ws; ws += (size_t)(ML + 1) * DI * 4;  // 33.5 MB (+pad row)
  float*  dtp   = ws; ws += (size_t)ML * 32;
  float*  bccf  = ws; ws += (size_t)(ML + 1) * 16 * 4;      // float4[(ML+1)*16]
  float*  lamv  = ws; ws += ML;
  float2* aggA  = (float2*)ws; ws += (size_t)NCHUNK * NLANES * 2;
  float2* aggU  = (float2*)ws; ws += (size_t)NCHUNK * NLANES * 2;
  float2* hp    = (float2*)ws; ws += (size_t)NCHUNK * NLANES * 2;
  unsigned short* xb   = (unsigned short*)ws; ws += (size_t)ML * DM / 2;
  unsigned short* wb1  = (unsigned short*)ws; ws += (size_t)(2 * DI) * DM / 2;
  unsigned short* wb2  = (unsigned short*)ws; ws += (size_t)DM * DI / 2;
  unsigned short* ybuf = (unsigned short*)ws; ws += (size_t)ML * DI / 2;

  const int n0 = ML * DM / 4, n1 = 2 * DI * DM / 4, n2 = DM * DI / 4;
  cvt3_k<<<(n0 + n1 + n2 + 255) / 256, 256, 0, stream>>>(x, xb, n0, in_proj, wb1, n1,
                                                         out_proj, wb2, n2);
  gemm_bf16<<<dim3(2 * DI / 128, ML / 128), 256, 0, stream>>>(
      (const short*)xb, (const short*)wb1, xz, ML, 2 * DI, DM);
  conv_silu_k<<<ML * DI / 256, 256, 0, stream>>>(xz, conv_w, conv_b, xc, sz);
  proj_k<<<ML / 2, 128, 0, stream>>>(xc, x_proj_w, dtp, bccf, lamv);
  delta_k<<<dim3(DI / 256, ML / 8), 256, 0, stream>>>(dtp, dt_w, dt_b, xc, lamv, dxbg);
  scan_pass<false><<<dim3(128, NCHUNK - 1), 256, 0, stream>>>(
      dxbg, (const float4*)bccf, sz, A_log, A_imag, D_skip,
      aggA, aggU, nullptr, nullptr);
  scan_combine_k<<<NLANES / 256, 256, 0, stream>>>(aggA, aggU, hp);
  scan_pass<true><<<dim3(128, NCHUNK), 256, 0, stream>>>(
      dxbg, (const float4*)bccf, sz, A_log, A_imag, D_skip,
      nullptr, nullptr, hp, ybuf);
  gemm_bf16<<<dim3(DM / 128, ML / 128), 256, 0, stream>>>(
      (const short*)ybuf, (const short*)wb2, out, ML, DM, DI);
}

// Round 5
// 201.539 us; speedup vs baseline: 1.8388x; 1.1055x over previous
//
#include <hip/hip_runtime.h>

// Mamba block forward. Round 5: scan algebra diet + NCHUNK=32, in-place
// prefix combine, K-split proj, 64x64 GEMM tiles, float4 conv.
constexpr int B  = 2, L = 1024, DM = 512, DI = 1024, NST = 16, PW = 97;
constexpr int ML = B * L;                   // 2048 rows
constexpr int NCHUNK = 32, CL = L / NCHUNK; // 32 chunks x 32 steps
constexpr int NLANES = B * DI * NST;        // 32768 scan lanes

#define DEV_INLINE __device__ __forceinline__

typedef __attribute__((ext_vector_type(8))) short bf16x8;   // 8 bf16 (4 VGPRs)
typedef __attribute__((ext_vector_type(4))) float f32x4;    // 4 fp32 acc

DEV_INLINE float sigmoidf_(float x) { return 1.f / (1.f + __expf(-x)); }
DEV_INLINE unsigned short f2bf(float f) {
  unsigned int u = __float_as_uint(f);
  return (unsigned short)((u + 0x7FFFu + ((u >> 16) & 1u)) >> 16);  // RNE
}

#if __has_builtin(__builtin_amdgcn_exp2f)
#define EXP2F(x) __builtin_amdgcn_exp2f(x)
#else
#define EXP2F(x) exp2f(x)
#endif
#if __has_builtin(__builtin_amdgcn_sinf)
#define SINR(x) __builtin_amdgcn_sinf(x)   // sin(2*pi*x), x in revolutions
#define COSR(x) __builtin_amdgcn_cosf(x)
#else
#define SINR(x) __sinf((x) * 6.2831853f)
#define COSR(x) __cosf((x) * 6.2831853f)
#endif

// ---------------------------------------------------------------------------
// f32 -> bf16 convert, 3 segments in one launch (x, in_proj_w, out_proj_w)
// ---------------------------------------------------------------------------
__global__ __launch_bounds__(256) void cvt3_k(
    const float* __restrict__ i0, unsigned short* __restrict__ o0, int n0,
    const float* __restrict__ i1, unsigned short* __restrict__ o1, int n1,
    const float* __restrict__ i2, unsigned short* __restrict__ o2, int n2) {
  int i = blockIdx.x * 256 + threadIdx.x;   // in float4 units
  const float* in; unsigned short* out; int off;
  if (i < n0)              { in = i0; out = o0; off = i; }
  else if (i < n0 + n1)    { in = i1; out = o1; off = i - n0; }
  else if (i < n0 + n1 + n2) { in = i2; out = o2; off = i - n0 - n1; }
  else return;
  float4 v = ((const float4*)in)[off];
  ((ushort4*)out)[off] = make_ushort4(f2bf(v.x), f2bf(v.y), f2bf(v.z), f2bf(v.w));
}

// ---------------------------------------------------------------------------
// bf16 MFMA GEMM, 64x64 tile, BK=64, 4 waves (wave w = 16 rows), XOR-swizzled
// LDS. C(M,N) f32 = A(M,K)bf16 @ W(N,K)bf16^T.
// ---------------------------------------------------------------------------
DEV_INLINE int swz(int row, int kb) { return (row << 7) + (kb ^ ((row & 7) << 4)); }

__global__ __launch_bounds__(256) void gemm_bf16_64(
    const short* __restrict__ A, const short* __restrict__ W,
    float* __restrict__ C, int M, int N, int K) {
  __shared__ char ldsb[16384];               // A [0,8K), W [8K,16K)
  const int tid = threadIdx.x;
  const int lane = tid & 63, wv = tid >> 6;
  const int bm = blockIdx.y * 64, bn = blockIdx.x * 64;

  f32x4 acc[4];
#pragma unroll
  for (int nb = 0; nb < 4; ++nb) acc[nb] = (f32x4){0.f, 0.f, 0.f, 0.f};

  for (int k0 = 0; k0 < K; k0 += 64) {
#pragma unroll
    for (int i = 0; i < 2; ++i) {
      int off = i * 4096 + tid * 16;
      int row = off >> 7, kb = off & 127;
      bf16x8 va = *(const bf16x8*)(A + (size_t)(bm + row) * K + k0 + (kb >> 1));
      bf16x8 vw = *(const bf16x8*)(W + (size_t)(bn + row) * K + k0 + (kb >> 1));
      *(bf16x8*)(ldsb + swz(row, kb)) = va;
      *(bf16x8*)(ldsb + 8192 + swz(row, kb)) = vw;
    }
    __syncthreads();
#pragma unroll
    for (int ks = 0; ks < 2; ++ks) {
      const int kb = ks * 64 + ((lane >> 4) << 4);
      bf16x8 af = *(const bf16x8*)(ldsb + swz(wv * 16 + (lane & 15), kb));
#pragma unroll
      for (int nb = 0; nb < 4; ++nb) {
        bf16x8 bfv = *(const bf16x8*)(ldsb + 8192 + swz(nb * 16 + (lane & 15), kb));
        acc[nb] = __builtin_amdgcn_mfma_f32_16x16x32_bf16(af, bfv, acc[nb], 0, 0, 0);
      }
    }
    __syncthreads();
  }
#pragma unroll
  for (int nb = 0; nb < 4; ++nb) {
    int col = bn + nb * 16 + (lane & 15);
    int row0 = bm + wv * 16 + ((lane >> 4) << 2);
#pragma unroll
    for (int j = 0; j < 4; ++j)
      C[(size_t)(row0 + j) * N + col] = acc[nb][j];
  }
}

// ---------------------------------------------------------------------------
// causal depthwise conv (K=3) + bias + SiLU -> xc; silu(z) -> sz. float4.
// ---------------------------------------------------------------------------
__global__ __launch_bounds__(256) void conv_silu_k(
    const float* __restrict__ xz, const float* __restrict__ cw,
    const float* __restrict__ cb, float* __restrict__ xc, float* __restrict__ sz) {
  int idx = blockIdx.x * 256 + threadIdx.x;   // float4 unit: (m, d4)
  int m = idx >> 8, d4 = (idx & 255) * 4;
  int t = m & (L - 1);
  const float* base = xz + (size_t)m * (2 * DI);
  float4 r2 = *(const float4*)(base + d4);
  float4 r1 = (t >= 1) ? *(const float4*)(base - 2 * DI + d4) : make_float4(0, 0, 0, 0);
  float4 r0 = (t >= 2) ? *(const float4*)(base - 4 * DI + d4) : make_float4(0, 0, 0, 0);
  float4 zv = *(const float4*)(base + DI + d4);
  float wv[12];
  *(float4*)(wv + 0) = *(const float4*)(cw + d4 * 3 + 0);
  *(float4*)(wv + 4) = *(const float4*)(cw + d4 * 3 + 4);
  *(float4*)(wv + 8) = *(const float4*)(cw + d4 * 3 + 8);
  float4 bv = *(const float4*)(cb + d4);
  float rin0[4] = {r0.x, r0.y, r0.z, r0.w};
  float rin1[4] = {r1.x, r1.y, r1.z, r1.w};
  float rin2[4] = {r2.x, r2.y, r2.z, r2.w};
  float bb[4] = {bv.x, bv.y, bv.z, bv.w};
  float zz[4] = {zv.x, zv.y, zv.z, zv.w};
  float xo[4], zo[4];
#pragma unroll
  for (int j = 0; j < 4; ++j) {
    float v = bb[j];
    v = fmaf(rin0[j], wv[3 * j + 0], v);
    v = fmaf(rin1[j], wv[3 * j + 1], v);
    v = fmaf(rin2[j], wv[3 * j + 2], v);
    xo[j] = v * sigmoidf_(v);
    zo[j] = zz[j] * sigmoidf_(zz[j]);
  }
  *(float4*)(xc + (size_t)idx * 4) = make_float4(xo[0], xo[1], xo[2], xo[3]);
  *(float4*)(sz + (size_t)idx * 4) = make_float4(zo[0], zo[1], zo[2], zo[3]);
}

// ---------------------------------------------------------------------------
// x_proj: (ML,1024) x (97,1024)^T, K split 4 ways (q=tid>>7), LDS combine,
// scattered into scan layouts: dtp, bcc {Br,Bi,Cr,Ci}, lamv (sigmoided).
// ---------------------------------------------------------------------------
__global__ __launch_bounds__(512) void proj_k(
    const float* __restrict__ xc, const float* __restrict__ xw,
    float* __restrict__ dtp, float* __restrict__ bccf, float* __restrict__ lamv) {
  __shared__ float xs[4][DI];
  __shared__ float pt[3][4][128];
  const int tid = threadIdx.x;
  const int m0 = blockIdx.x * 4;
  const int nn = tid & 127, qq = tid >> 7;
  for (int i = tid; i < 4 * DI; i += 512)
    xs[i >> 10][i & 1023] = xc[(size_t)m0 * DI + i];
  __syncthreads();
  float s0 = 0.f, s1 = 0.f, s2 = 0.f, s3 = 0.f;
  if (nn < PW) {
    const float* wr = xw + (size_t)nn * DI + qq * 256;
    const int kb = qq * 256;
#pragma unroll 4
    for (int k = 0; k < 256; k += 4) {
      float4 w4 = *(const float4*)(wr + k);
      s0 = fmaf(xs[0][kb + k], w4.x, s0); s0 = fmaf(xs[0][kb + k + 1], w4.y, s0);
      s0 = fmaf(xs[0][kb + k + 2], w4.z, s0); s0 = fmaf(xs[0][kb + k + 3], w4.w, s0);
      s1 = fmaf(xs[1][kb + k], w4.x, s1); s1 = fmaf(xs[1][kb + k + 1], w4.y, s1);
      s1 = fmaf(xs[1][kb + k + 2], w4.z, s1); s1 = fmaf(xs[1][kb + k + 3], w4.w, s1);
      s2 = fmaf(xs[2][kb + k], w4.x, s2); s2 = fmaf(xs[2][kb + k + 1], w4.y, s2);
      s2 = fmaf(xs[2][kb + k + 2], w4.z, s2); s2 = fmaf(xs[2][kb + k + 3], w4.w, s2);
      s3 = fmaf(xs[3][kb + k], w4.x, s3); s3 = fmaf(xs[3][kb + k + 1], w4.y, s3);
      s3 = fmaf(xs[3][kb + k + 2], w4.z, s3); s3 = fmaf(xs[3][kb + k + 3], w4.w, s3);
    }
    if (qq > 0) {
      pt[qq - 1][0][nn] = s0; pt[qq - 1][1][nn] = s1;
      pt[qq - 1][2][nn] = s2; pt[qq - 1][3][nn] = s3;
    }
  }
  __syncthreads();
  if (qq == 0 && nn < PW) {
    s0 += pt[0][0][nn] + pt[1][0][nn] + pt[2][0][nn];
    s1 += pt[0][1][nn] + pt[1][1][nn] + pt[2][1][nn];
    s2 += pt[0][2][nn] + pt[1][2][nn] + pt[2][2][nn];
    s3 += pt[0][3][nn] + pt[1][3][nn] + pt[2][3][nn];
    float sv[4] = {s0, s1, s2, s3};
#pragma unroll
    for (int r = 0; r < 4; ++r) {
      int m = m0 + r;
      float s = sv[r];
      if (nn < 32)        dtp[m * 32 + nn] = s;
      else if (nn < 48)   bccf[(m * 16 + nn - 32) * 4 + 0] = s;
      else if (nn < 64)   bccf[(m * 16 + nn - 48) * 4 + 1] = s;
      else if (nn < 80)   bccf[(m * 16 + nn - 64) * 4 + 2] = s;
      else if (nn < 96)   bccf[(m * 16 + nn - 80) * 4 + 3] = s;
      else                lamv[m] = sigmoidf_(s);
    }
  }
}

// ---------------------------------------------------------------------------
// delta = softplus(dtp @ dt_w^T + dt_b); emit packed float4 {dlt, xt, bsc, g}
// ---------------------------------------------------------------------------
__global__ __launch_bounds__(256) void delta_k(
    const float* __restrict__ dtp, const float* __restrict__ dtw,
    const float* __restrict__ dtb, const float* __restrict__ xc,
    const float* __restrict__ lamv, float4* __restrict__ dxbg) {
  __shared__ float ws[256][33];
  __shared__ float ps[8][32];
  const int tid = threadIdx.x;
  const int d0 = blockIdx.x * 256;
  const int m0 = blockIdx.y * 8;
#pragma unroll
  for (int j = 0; j < 8; ++j) {
    int flat = tid * 4 + j * 1024;
    int r = flat >> 5, c = flat & 31;
    float4 v = *(const float4*)(dtw + (size_t)d0 * 32 + flat);
    ws[r][c] = v.x; ws[r][c + 1] = v.y; ws[r][c + 2] = v.z; ws[r][c + 3] = v.w;
  }
  { int i = tid >> 5, r = tid & 31;
    ps[i][r] = dtp[(size_t)(m0 + i) * 32 + r]; }
  __syncthreads();
  float s[8];
  float bias = dtb[d0 + tid];
#pragma unroll
  for (int i = 0; i < 8; ++i) s[i] = bias;
#pragma unroll
  for (int r = 0; r < 32; ++r) {
    float wv = ws[tid][r];
#pragma unroll
    for (int i = 0; i < 8; ++i) s[i] = fmaf(ps[i][r], wv, s[i]);
  }
#pragma unroll
  for (int i = 0; i < 8; ++i) {
    float x = s[i];
    float dlt = (x > 20.f) ? x : log1pf(__expf(x));
    int m = m0 + i;
    float xt = xc[(size_t)m * DI + d0 + tid];
    float lam = lamv[m];
    dxbg[(size_t)m * DI + d0 + tid] = make_float4(dlt, xt, (1.f - lam) * dlt, lam * dlt);
  }
}

// ---------------------------------------------------------------------------
// Chunked selective scan. lane = n (0..15); 16 (b,d) channels per block.
// Recurrence (algebraically == reference):
//   h_t = alpha * (h_{t-1} + bsc*Bx_{t-1}) + g*Bx_t,  bsc=(1-lam)dlt, g=lam*dlt
// PASS_A (c=0..30): aggregate prod(alpha) via S=sum(dlt), U=h -> aggA/aggU.
// combine: in-place prefix into aggU (slot c-1 holds chunk-c entry state).
// PASS_B (c=0..31): rescan from prefix, emit ybuf bf16.
// ---------------------------------------------------------------------------
template <bool PASS_B>
__global__ __launch_bounds__(256) void scan_pass(
    const float4* __restrict__ dxbg, const float4* __restrict__ bcc,
    const float* __restrict__ sz,
    const float* __restrict__ A_log, const float* __restrict__ A_imag,
    const float* __restrict__ D_skip,
    float2* __restrict__ aggA, float2* __restrict__ aggU,
    unsigned short* __restrict__ ybuf) {
  const int tid = threadIdx.x;
  const int n = tid & 15;
  const int gch = blockIdx.x * 16 + (tid >> 4);
  const int c = blockIdx.y;
  const int b = gch >> 10, d = gch & 1023;
  const int lane = blockIdx.x * 256 + tid;
  const float Ar = -__expf(A_log[d * 16 + n]);
  const float Arl = Ar * 1.44269504f;                  // * log2(e)
  const float Airv = A_imag[d * 16 + n] * 0.15915494f; // / (2*pi)
  const int t0 = c * CL, mb = b * L;
  const unsigned ix0 = (unsigned)(mb + t0) * DI + d;

  float Bxpr = 0.f, Bxpi = 0.f;
  if (c > 0) {
    float xp = dxbg[ix0 - DI].y;
    float4 bp = bcc[(mb + t0 - 1) * 16 + n];
    Bxpr = bp.x * xp; Bxpi = bp.y * xp;
  }
  float hr = 0.f, hi = 0.f, S = 0.f, Dsk = 0.f;
  if (PASS_B) {
    if (c > 0) {
      float2 h0 = aggU[(c - 1) * NLANES + lane];  // prefix from combine
      hr = h0.x; hi = h0.y;
    }
    Dsk = D_skip[d];
  }

  const float4* qp = dxbg + ix0;
  const float4* pp = bcc + (size_t)(mb + t0) * 16 + n;
#pragma unroll 4
  for (int t = 0; t < CL; ++t) {
    float4 q = qp[(size_t)t * DI];      // {dlt, xt, bsc, g}
    float4 p = pp[(size_t)t * 16];      // {Br, Bi, Cr, Ci}
    float ear = EXP2F(q.x * Arl);
    float rv = q.x * Airv;
    float sn = SINR(rv), cs = COSR(rv);
    float ar = ear * cs, ai = ear * sn;
    float Bxr = p.x * q.y, Bxi = p.y * q.y;
    float wr = fmaf(q.z, Bxpr, hr), wi = fmaf(q.z, Bxpi, hi);
    hr = fmaf(q.w, Bxr, fmaf(-ai, wi, ar * wr));
    hi = fmaf(q.w, Bxi, fmaf(ai, wr, ar * wi));
    Bxpr = Bxr; Bxpi = Bxi;
    if (!PASS_B) {
      S += q.x;
    } else {
      float yc = fmaf(hi, p.w, hr * p.z);  // Re(h * conj(C))
      yc += __shfl_xor(yc, 1);
      yc += __shfl_xor(yc, 2);
      yc += __shfl_xor(yc, 4);
      yc += __shfl_xor(yc, 8);
      if (n == 0) {
        unsigned ixm = ix0 + ((unsigned)t << 10);
        float y = fmaf(Dsk, q.y, yc);
        ybuf[ixm] = f2bf(y * sz[ixm]);
      }
    }
  }
  if (!PASS_B) {
    float earS = EXP2F(S * Arl);
    float rvS = S * Airv;
    float AaR = earS * COSR(rvS);
    float AaI = earS * SINR(rvS);
    int idx = c * NLANES + lane;
    aggA[idx] = make_float2(AaR, AaI);
    aggU[idx] = make_float2(hr, hi);
  }
}

// in-place prefix: after this, aggU[c] = chunk-(c+1) entry state
__global__ __launch_bounds__(256) void scan_combine_k(
    const float2* __restrict__ aggA, float2* __restrict__ aggU) {
  int gid = blockIdx.x * 256 + threadIdx.x;
  float hr = 0.f, hi = 0.f;
#pragma unroll
  for (int c = 0; c < NCHUNK - 1; ++c) {
    float2 a = aggA[c * NLANES + gid];
    float2 u = aggU[c * NLANES + gid];
    float nr = fmaf(a.x, hr, fmaf(-a.y, hi, u.x));
    float ni = fmaf(a.x, hi, fmaf(a.y, hr, u.y));
    hr = nr; hi = ni;
    aggU[c * NLANES + gid] = make_float2(hr, hi);
  }
}

extern "C" void kernel_launch(void* const* d_in, const int* in_sizes, int n_in,
                              void* d_out, int out_size, void* d_ws, size_t ws_size,
                              hipStream_t stream) {
  const float* x        = (const float*)d_in[0];
  const float* in_proj  = (const float*)d_in[1];
  const float* conv_w   = (const float*)d_in[2];
  const float* conv_b   = (const float*)d_in[3];
  const float* x_proj_w = (const float*)d_in[4];
  const float* dt_w     = (const float*)d_in[5];
  const float* dt_b     = (const float*)d_in[6];
  const float* A_log    = (const float*)d_in[7];
  const float* A_imag   = (const float*)d_in[8];
  const float* D_skip   = (const float*)d_in[9];
  const float* out_proj = (const float*)d_in[10];
  float* out = (float*)d_out;

  float* ws = (float*)d_ws;
  float*  xz    = ws; ws += (size_t)ML * 2 * DI;                 // 16.8 MB
  float*  xc    = ws; ws += (size_t)ML * DI;                     //  8.4 MB
  float*  sz    = ws; ws += (size_t)ML * DI;                     //  8.4 MB
  float4* dxbg  = (float4*)ws; ws += (size_t)(ML + 1) * DI * 4;  // 33.6 MB
  float*  dtp   = ws; ws += (size_t)ML * 32;
  float*  bccf  = ws; ws += (size_t)(ML + 1) * 16 * 4;
  float*  lamv  = ws; ws += ML;
  float2* aggA  = (float2*)ws; ws += (size_t)NCHUNK * NLANES * 2; // 8.4 MB
  float2* aggU  = (float2*)ws; ws += (size_t)NCHUNK * NLANES * 2; // 8.4 MB
  unsigned short* xb   = (unsigned short*)ws; ws += (size_t)ML * DM / 2;
  unsigned short* wb1  = (unsigned short*)ws; ws += (size_t)(2 * DI) * DM / 2;
  unsigned short* wb2  = (unsigned short*)ws; ws += (size_t)DM * DI / 2;
  unsigned short* ybuf = (unsigned short*)ws; ws += (size_t)ML * DI / 2;  // ~94 MB total

  const int n0 = ML * DM / 4, n1 = 2 * DI * DM / 4, n2 = DM * DI / 4;
  cvt3_k<<<(n0 + n1 + n2 + 255) / 256, 256, 0, stream>>>(x, xb, n0, in_proj, wb1, n1,
                                                         out_proj, wb2, n2);
  gemm_bf16_64<<<dim3(2 * DI / 64, ML / 64), 256, 0, stream>>>(
      (const short*)xb, (const short*)wb1, xz, ML, 2 * DI, DM);
  conv_silu_k<<<ML * DI / 4 / 256, 256, 0, stream>>>(xz, conv_w, conv_b, xc, sz);
  proj_k<<<ML / 4, 512, 0, stream>>>(xc, x_proj_w, dtp, bccf, lamv);
  delta_k<<<dim3(DI / 256, ML / 8), 256, 0, stream>>>(dtp, dt_w, dt_b, xc, lamv, dxbg);
  scan_pass<false><<<dim3(128, NCHUNK - 1), 256, 0, stream>>>(
      dxbg, (const float4*)bccf, sz, A_log, A_imag, D_skip, aggA, aggU, nullptr);
  scan_combine_k<<<NLANES / 256, 256, 0, stream>>>(aggA, aggU);
  scan_pass<true><<<dim3(128, NCHUNK), 256, 0, stream>>>(
      dxbg, (const float4*)bccf, sz, A_log, A_imag, D_skip, aggA, aggU, ybuf);
  gemm_bf16_64<<<dim3(DM / 64, ML / 64), 256, 0, stream>>>(
      (const short*)ybuf, (const short*)wb2, out, ML, DM, DI);
}